// Round 1
// baseline (1137.105 us; speedup 1.0000x reference)
//
#include <hip/hip_runtime.h>

// CNN encoder: 6 convs (2 with per-sample meta weights), 5 training-mode BNs, lrelu.
// Round 1: direct-conv templated kernel, bf16 intermediates (threshold is 2% rel),
// fp32 accumulation, BN fused into next layer's input load, deterministic 2-stage
// BN stats reduction (no atomics).

#define LRELU_NEG 0.2f
#define BN_EPS 1e-5f

__device__ __forceinline__ float bf2f(unsigned short u) {
  union { unsigned int i; float f; } v; v.i = ((unsigned int)u) << 16; return v.f;
}
__device__ __forceinline__ unsigned short f2bf(float f) {
  unsigned int x = __float_as_uint(f);
  x += 0x7FFFu + ((x >> 16) & 1u);   // round-to-nearest-even
  return (unsigned short)(x >> 16);
}
__device__ __forceinline__ float lrelu(float v) { return v < 0.f ? LRELU_NEG * v : v; }

// ---------------------------------------------------------------------------
// Prep: assemble per-sample weight tensors for meta layers 1 & 2.
// wl1: [16][8][3*25]  (oc<4: shared w11, else conv_weights[:, :300])
// wl2: [16][16][8*25] (oc<8: shared w12, else conv_weights[:, 300:1900])
// ---------------------------------------------------------------------------
__global__ void prep_l1(const float* __restrict__ w11, const float* __restrict__ b11,
                        const float* __restrict__ cw, float* __restrict__ wl1,
                        float* __restrict__ bl1) {
  int i = blockIdx.x * 256 + threadIdx.x;
  if (i < 9600) {            // 16*8*75
    int b = i / 600, r = i % 600;
    int oc = r / 75, t = r % 75;
    wl1[i] = (oc < 4) ? w11[oc * 75 + t] : cw[b * 1900 + (oc - 4) * 75 + t];
  }
  if (i < 8) bl1[i] = (i < 4) ? b11[i] : 0.f;
}

__global__ void prep_l2(const float* __restrict__ w12, const float* __restrict__ b12,
                        const float* __restrict__ cw, float* __restrict__ wl2,
                        float* __restrict__ bl2) {
  int i = blockIdx.x * 256 + threadIdx.x;
  if (i < 51200) {           // 16*16*200
    int b = i / 3200, r = i % 3200;
    int oc = r / 200, t = r % 200;
    wl2[i] = (oc < 8) ? w12[oc * 200 + t] : cw[b * 1900 + 300 + (oc - 8) * 200 + t];
  }
  if (i < 16) bl2[i] = (i < 8) ? b12[i] : 0.f;
}

// ---------------------------------------------------------------------------
// Generic direct conv.
//   16x16 output tile per block, 256 threads = 4 oc-groups x 64 pixel slots,
//   each thread: 4 pixels (rows sy0+4k) x OC_PER_T channels.
//   Input tile + oc-transposed weights staged in LDS.
//   IN_BN: apply scale/shift (+lrelu) of PREVIOUS layer's BN on input load
//          (OOB stays 0 -> matches padding of post-activation tensor).
//   OUT_LRELU: lrelu before store (layer 1 only; others store pre-BN).
// ---------------------------------------------------------------------------
template <int IN_C, int IC_CHUNK, int OC_PER_T, int K, int S, bool IN_BN,
          bool OUT_LRELU, bool IN_F32>
__global__ __launch_bounds__(256) void conv_kernel(
    const void* __restrict__ in_, const float* __restrict__ wgt,
    const float* __restrict__ bias, const float* __restrict__ stats,
    unsigned short* __restrict__ out, int H, int W, int OH, int OW, int OC_TOT,
    int wstride) {
  constexpr int OC_BLOCK = OC_PER_T * 4;
  constexpr int P = (K == 5) ? 2 : 1;
  constexpr int IN_TILE = 15 * S + K;
  constexpr int IN_CNT = IC_CHUNK * IN_TILE * IN_TILE;
  constexpr int W_CNT = IC_CHUNK * K * K * OC_BLOCK;

  __shared__ float s_in[IN_CNT];
  __shared__ float s_w[W_CNT];

  const int tid = threadIdx.x;
  const int b = blockIdx.z;
  const int oc0 = blockIdx.y * OC_BLOCK;
  const int ntx = OW >> 4;
  const int tx = blockIdx.x % ntx, ty = blockIdx.x / ntx;
  const int x0 = tx * 16 * S - P, y0 = ty * 16 * S - P;

  const int ocg = tid >> 6;          // 0..3
  const int pslot = tid & 63;
  const int sx = pslot & 15;         // column 0..15
  const int sy0 = pslot >> 4;        // rows sy0, sy0+4, sy0+8, sy0+12

  float acc[4][OC_PER_T];
#pragma unroll
  for (int k = 0; k < 4; k++)
#pragma unroll
    for (int j = 0; j < OC_PER_T; j++) acc[k][j] = 0.f;

  const float* wbase = wgt + (size_t)b * wstride;

  for (int c0 = 0; c0 < IN_C; c0 += IC_CHUNK) {
    // --- stage input tile (with fused BN+lrelu of previous layer) ---
    for (int e = tid; e < IN_CNT; e += 256) {
      int ic = e / (IN_TILE * IN_TILE);
      int r = e % (IN_TILE * IN_TILE);
      int iy = r / IN_TILE, ix = r % IN_TILE;
      int gy = y0 + iy, gx = x0 + ix;
      float v = 0.f;
      if (gy >= 0 && gy < H && gx >= 0 && gx < W) {
        size_t gidx = (((size_t)b * IN_C + c0 + ic) * H + gy) * W + gx;
        v = IN_F32 ? ((const float*)in_)[gidx]
                   : bf2f(((const unsigned short*)in_)[gidx]);
        if (IN_BN) {
          v = v * stats[(c0 + ic) * 2] + stats[(c0 + ic) * 2 + 1];
          v = lrelu(v);
        }
      }
      s_in[e] = v;
    }
    // --- stage weights, transposed so oc is contiguous ---
    for (int e = tid; e < W_CNT; e += 256) {
      int ocl = e % OC_BLOCK;
      int rest = e / OC_BLOCK;           // ic*K*K + ky*K + kx
      int ic = rest / (K * K), kk = rest % (K * K);
      s_w[rest * OC_BLOCK + ocl] =
          wbase[((size_t)(oc0 + ocl) * IN_C + c0 + ic) * (K * K) + kk];
    }
    __syncthreads();

    // --- accumulate ---
    for (int ic = 0; ic < IC_CHUNK; ic++)
      for (int ky = 0; ky < K; ky++)
#pragma unroll
        for (int kx = 0; kx < K; kx++) {
          float xv[4];
#pragma unroll
          for (int k = 0; k < 4; k++)
            xv[k] = s_in[(ic * IN_TILE + (sy0 + 4 * k) * S + ky) * IN_TILE +
                         sx * S + kx];
          const float* wp =
              &s_w[(ic * K * K + ky * K + kx) * OC_BLOCK + ocg * OC_PER_T];
#pragma unroll
          for (int j = 0; j < OC_PER_T; j++) {
            float wv = wp[j];
#pragma unroll
            for (int k = 0; k < 4; k++) acc[k][j] = fmaf(xv[k], wv, acc[k][j]);
          }
        }
    __syncthreads();
  }

  // --- epilogue: +bias (optional lrelu), store bf16 ---
#pragma unroll
  for (int j = 0; j < OC_PER_T; j++) {
    int oc = oc0 + ocg * OC_PER_T + j;
    float bv = bias[oc];
#pragma unroll
    for (int k = 0; k < 4; k++) {
      int oy = ty * 16 + sy0 + 4 * k, ox = tx * 16 + sx;
      float v = acc[k][j] + bv;
      if (OUT_LRELU) v = lrelu(v);
      out[(((size_t)b * OC_TOT + oc) * OH + oy) * OW + ox] = f2bf(v);
    }
  }
}

// ---------------------------------------------------------------------------
// BN stats: 2-stage deterministic reduction over (N,H,W) per channel.
// ---------------------------------------------------------------------------
__global__ __launch_bounds__(256) void bn_stage1(const unsigned short* __restrict__ y,
                                                 float* __restrict__ part, int C,
                                                 int HW, int NB) {
  int c = blockIdx.x / NB, nb = blockIdx.x % NB;
  int chunk = HW / NB;
  float s = 0.f, sq = 0.f;
  for (int b = 0; b < 16; b++) {
    const unsigned short* p = y + ((size_t)b * C + c) * HW + (size_t)nb * chunk;
    for (int i = threadIdx.x * 4; i < chunk; i += 1024) {
      ushort4 u = *reinterpret_cast<const ushort4*>(p + i);
      float v0 = bf2f(u.x), v1 = bf2f(u.y), v2 = bf2f(u.z), v3 = bf2f(u.w);
      s += v0 + v1 + v2 + v3;
      sq += v0 * v0 + v1 * v1 + v2 * v2 + v3 * v3;
    }
  }
  for (int o = 32; o > 0; o >>= 1) {
    s += __shfl_down(s, o);
    sq += __shfl_down(sq, o);
  }
  __shared__ float rs[4], rq[4];
  if ((threadIdx.x & 63) == 0) {
    rs[threadIdx.x >> 6] = s;
    rq[threadIdx.x >> 6] = sq;
  }
  __syncthreads();
  if (threadIdx.x == 0) {
    part[blockIdx.x * 2] = rs[0] + rs[1] + rs[2] + rs[3];
    part[blockIdx.x * 2 + 1] = rq[0] + rq[1] + rq[2] + rq[3];
  }
}

__global__ void bn_stage2(const float* __restrict__ part, const float* __restrict__ g,
                          const float* __restrict__ bb, float* __restrict__ stats,
                          int NB, float invN) {
  int c = blockIdx.x;
  float s = 0.f, sq = 0.f;
  for (int i = threadIdx.x; i < NB; i += 64) {
    s += part[(c * NB + i) * 2];
    sq += part[(c * NB + i) * 2 + 1];
  }
  for (int o = 32; o > 0; o >>= 1) {
    s += __shfl_down(s, o);
    sq += __shfl_down(sq, o);
  }
  if (threadIdx.x == 0) {
    float m = s * invN;
    float var = sq * invN - m * m;
    float sc = g[c] * rsqrtf(var + BN_EPS);
    stats[c * 2] = sc;
    stats[c * 2 + 1] = bb[c] - m * sc;
  }
}

// final: out = lrelu(bn(y6)) as fp32
__global__ void bn_apply_out(const unsigned short* __restrict__ y,
                             const float* __restrict__ stats, float* __restrict__ out,
                             int total, int HW, int C) {
  int i = blockIdx.x * 256 + threadIdx.x;
  if (i < total) {
    int c = (i / HW) % C;
    float v = bf2f(y[i]) * stats[c * 2] + stats[c * 2 + 1];
    out[i] = lrelu(v);
  }
}

// ---------------------------------------------------------------------------
extern "C" void kernel_launch(void* const* d_in, const int* in_sizes, int n_in,
                              void* d_out, int out_size, void* d_ws, size_t ws_size,
                              hipStream_t stream) {
  const float* x    = (const float*)d_in[0];
  const float* cw   = (const float*)d_in[1];
  const float* w11  = (const float*)d_in[2];
  const float* b11  = (const float*)d_in[3];
  const float* w12  = (const float*)d_in[4];
  const float* b12  = (const float*)d_in[5];
  const float* bn1g = (const float*)d_in[6];
  const float* bn1b = (const float*)d_in[7];
  const float* c2w[4] = {(const float*)d_in[8], (const float*)d_in[12],
                         (const float*)d_in[16], (const float*)d_in[20]};
  const float* c2b[4] = {(const float*)d_in[9], (const float*)d_in[13],
                         (const float*)d_in[17], (const float*)d_in[21]};
  const float* bng[4] = {(const float*)d_in[10], (const float*)d_in[14],
                         (const float*)d_in[18], (const float*)d_in[22]};
  const float* bnb[4] = {(const float*)d_in[11], (const float*)d_in[15],
                         (const float*)d_in[19], (const float*)d_in[23]};

  char* ws = (char*)d_ws;
  // ping-pong activation buffers (bf16): A=67MB, B=33.5MB
  unsigned short* bufA = (unsigned short*)(ws);
  unsigned short* bufB = (unsigned short*)(ws + 67108864);
  float* wl1 = (float*)(ws + 100663296);
  float* bl1 = wl1 + 9600;
  float* wl2 = bl1 + 8;
  float* bl2 = wl2 + 51200;
  float* part = bl2 + 16;       // up to 1024 (sum,sumsq) pairs
  float* stats2 = part + 2048;  // C=16
  float* stats3 = stats2 + 32;  // C=32
  float* stats4 = stats3 + 64;  // C=64
  float* stats5 = stats4 + 128; // C=128
  float* stats6 = stats5 + 256; // C=128

  prep_l1<<<38, 256, 0, stream>>>(w11, b11, cw, wl1, bl1);
  prep_l2<<<200, 256, 0, stream>>>(w12, b12, cw, wl2, bl2);

  // L1: 3->8, k5 s1 p2, 512^2 -> 512^2, per-sample weights, lrelu out -> h1(bufA)
  conv_kernel<3, 3, 2, 5, 1, false, true, true>
      <<<dim3(32 * 32, 1, 16), 256, 0, stream>>>(x, wl1, bl1, nullptr, bufA, 512,
                                                 512, 512, 512, 8, 600);
  // L2: 8->16, k5 s2 p2, 512^2 -> 256^2, per-sample weights, pre-BN -> y2(bufB)
  conv_kernel<8, 8, 4, 5, 2, false, false, false>
      <<<dim3(16 * 16, 1, 16), 256, 0, stream>>>(bufA, wl2, bl2, nullptr, bufB, 512,
                                                 512, 256, 256, 16, 3200);
  bn_stage1<<<16 * 64, 256, 0, stream>>>(bufB, part, 16, 65536, 64);
  bn_stage2<<<16, 64, 0, stream>>>(part, bn1g, bn1b, stats2, 64,
                                   1.f / (16.f * 65536.f));
  // S1: 16->32, k5 s2 p2, 256^2 -> 128^2 (BN2+lrelu fused on read) -> y3(bufA)
  conv_kernel<16, 8, 8, 5, 2, true, false, false>
      <<<dim3(8 * 8, 1, 16), 256, 0, stream>>>(bufB, c2w[0], c2b[0], stats2, bufA,
                                               256, 256, 128, 128, 32, 0);
  bn_stage1<<<32 * 32, 256, 0, stream>>>(bufA, part, 32, 16384, 32);
  bn_stage2<<<32, 64, 0, stream>>>(part, bng[0], bnb[0], stats3, 32,
                                   1.f / (16.f * 16384.f));
  // S2: 32->64, k5 s2 p2, 128^2 -> 64^2 -> y4(bufB)
  conv_kernel<32, 8, 8, 5, 2, true, false, false>
      <<<dim3(4 * 4, 2, 16), 256, 0, stream>>>(bufA, c2w[1], c2b[1], stats3, bufB,
                                               128, 128, 64, 64, 64, 0);
  bn_stage1<<<64 * 16, 256, 0, stream>>>(bufB, part, 64, 4096, 16);
  bn_stage2<<<64, 64, 0, stream>>>(part, bng[1], bnb[1], stats4, 16,
                                   1.f / (16.f * 4096.f));
  // S3: 64->128, k3 s2 p1, 64^2 -> 32^2 -> y5(bufA)
  conv_kernel<64, 8, 4, 3, 2, true, false, false>
      <<<dim3(2 * 2, 8, 16), 256, 0, stream>>>(bufB, c2w[2], c2b[2], stats4, bufA,
                                               64, 64, 32, 32, 128, 0);
  bn_stage1<<<128 * 8, 256, 0, stream>>>(bufA, part, 128, 1024, 8);
  bn_stage2<<<128, 64, 0, stream>>>(part, bng[2], bnb[2], stats5, 8,
                                    1.f / (16.f * 1024.f));
  // S4: 128->128, k3 s2 p1, 32^2 -> 16^2 -> y6(bufB)
  conv_kernel<128, 8, 4, 3, 2, true, false, false>
      <<<dim3(1, 8, 16), 256, 0, stream>>>(bufA, c2w[3], c2b[3], stats5, bufB, 32,
                                           32, 16, 16, 128, 0);
  bn_stage1<<<128 * 2, 256, 0, stream>>>(bufB, part, 128, 256, 2);
  bn_stage2<<<128, 64, 0, stream>>>(part, bng[3], bnb[3], stats6, 2,
                                    1.f / (16.f * 256.f));
  bn_apply_out<<<2048, 256, 0, stream>>>(bufB, stats6, (float*)d_out, 524288, 256,
                                         128);
}

// Round 2
// 317.803 us; speedup vs baseline: 3.5780x; 3.5780x over previous
//
#include <hip/hip_runtime.h>

// CNN encoder round 2: implicit-GEMM MFMA (bf16) for L2,S1..S4 over NHWC
// activations; LDS-tiled VALU direct conv for L1 (IC=3); deterministic
// 2-stage NHWC BatchNorm + in-place finalize.

typedef __attribute__((ext_vector_type(8))) short short8v;
typedef __attribute__((ext_vector_type(4))) float float4v;
typedef unsigned short u16;

#define LRELU_NEG 0.2f
#define BN_EPS 1e-5f

__device__ __forceinline__ float bf2f(u16 u){ union{unsigned i; float f;} v; v.i=(unsigned)u<<16; return v.f; }
__device__ __forceinline__ u16 f2bf(float f){ unsigned x=__float_as_uint(f); x += 0x7FFFu + ((x>>16)&1u); return (u16)(x>>16); }
__device__ __forceinline__ float lrelu(float v){ return v<0.f? LRELU_NEG*v : v; }

// ---------------------------------------------------------------------------
// x (NCHW f32) -> xpad (padded NHWC bf16 [16][517][518][3], pad T2/L2)
// ---------------------------------------------------------------------------
__global__ __launch_bounds__(256) void convert_x(const float* __restrict__ x, u16* __restrict__ xpad) {
  int i = blockIdx.x*256 + threadIdx.x;
  if (i >= 16*512*512) return;
  int b = i >> 18; int rem = i & 262143; int y = rem >> 9, xx = rem & 511;
  size_t dst = (((size_t)b*517 + y+2)*518 + xx+2)*3;
  size_t src = (size_t)b*786432 + rem;
  xpad[dst+0] = f2bf(x[src]);
  xpad[dst+1] = f2bf(x[src + 262144]);
  xpad[dst+2] = f2bf(x[src + 524288]);
}

__global__ void prep_bias(const float* __restrict__ b11, const float* __restrict__ b12,
                          float* __restrict__ bl1, float* __restrict__ bl2) {
  int t = threadIdx.x;
  if (t < 16) { bl1[t] = (t<4)? b11[t] : 0.f; bl2[t] = (t<8)? b12[t] : 0.f; }
}

// wl2m: [b][c=10][oc=16][kq=32]; chunk c=(ky, r): kk=r*32+kq -> kx=kk>>3, ic=kk&7
__global__ __launch_bounds__(256) void prep_l2m(const float* __restrict__ w12, const float* __restrict__ cw,
                                                u16* __restrict__ dst) {
  int i = blockIdx.x*256 + threadIdx.x;
  if (i >= 16*10*16*32) return;
  int kq = i & 31, oc = (i>>5) & 15, c = (i>>9) % 10, b = i / (10*16*32);
  int ky = c >> 1, r = c & 1;
  int kk = r*32 + kq; int kx = kk >> 3, ic = kk & 7;
  float v = 0.f;
  if (kx < 5)
    v = (oc < 8) ? w12[((oc*8+ic)*5+ky)*5+kx]
                 : cw[b*1900 + 300 + ((oc-8)*8+ic)*25 + ky*5 + kx];
  dst[i] = f2bf(v);
}

// shared-weight pack: dst[c][oc][32]; c=(ky,r), kk=r*32+kq -> kx=kk/IC, ic=kk%IC
template <int IC, int OC, int KSZ, int CPR, int NCH>
__global__ __launch_bounds__(256) void prep_w(const float* __restrict__ w, u16* __restrict__ dst) {
  int i = blockIdx.x*256 + threadIdx.x;
  if (i >= NCH*OC*32) return;
  int kq = i & 31, oc = (i>>5) % OC, c = i / (OC*32);
  int ky = c / CPR, r = c % CPR;
  int kk = r*32 + kq; int kx = kk / IC, ic = kk % IC;
  float v = (kx < KSZ) ? w[(((size_t)oc*IC + ic)*KSZ + ky)*KSZ + kx] : 0.f;
  dst[i] = f2bf(v);
}

// ---------------------------------------------------------------------------
// L1: 3->8 k5 s1 p2, per-sample weights. 32x32 px tile/block, thread = 4px x 8oc.
// ---------------------------------------------------------------------------
__global__ __launch_bounds__(256) void conv_l1(const u16* __restrict__ xpad,
    const float* __restrict__ w11, const float* __restrict__ cw,
    const float* __restrict__ bl1, u16* __restrict__ h1) {
  __shared__ float sx[36*36*3];
  __shared__ float sw[600];
  const int tid = threadIdx.x, b = blockIdx.z;
  const int tx0 = (blockIdx.x & 15) * 32, ty0 = (blockIdx.x >> 4) * 32;

  for (int e = tid; e < 36*36*3; e += 256) {
    int ic = e % 3; int rr = e / 3; int xx = rr % 36, yy = rr / 36;
    sx[e] = bf2f(xpad[(((size_t)b*517 + ty0+yy)*518 + tx0+xx)*3 + ic]);
  }
  for (int e = tid; e < 600; e += 256) {
    int oc = e & 7, k = e >> 3;
    int ic = k % 3, t2 = k / 3, kx = t2 % 5, ky = t2 / 5;
    sw[e] = (oc < 4) ? w11[((oc*3+ic)*5+ky)*5+kx]
                     : cw[b*1900 + ((oc-4)*3+ic)*25 + ky*5 + kx];
  }
  __syncthreads();

  const int px = tid & 31, py4 = (tid >> 5) * 4;
  float acc[4][8];
#pragma unroll
  for (int rr = 0; rr < 4; rr++)
#pragma unroll
    for (int j = 0; j < 8; j++) acc[rr][j] = bl1[j];

  for (int ky = 0; ky < 5; ky++)
    for (int kx = 0; kx < 5; kx++)
#pragma unroll
      for (int ic = 0; ic < 3; ic++) {
        const float* wp = &sw[((ky*5+kx)*3+ic)*8];
        float4v w0 = *(const float4v*)wp;
        float4v w1 = *(const float4v*)(wp+4);
        float v[4];
#pragma unroll
        for (int rr = 0; rr < 4; rr++)
          v[rr] = sx[((py4+rr+ky)*36 + px+kx)*3 + ic];
#pragma unroll
        for (int rr = 0; rr < 4; rr++) {
          acc[rr][0] = fmaf(v[rr], w0[0], acc[rr][0]);
          acc[rr][1] = fmaf(v[rr], w0[1], acc[rr][1]);
          acc[rr][2] = fmaf(v[rr], w0[2], acc[rr][2]);
          acc[rr][3] = fmaf(v[rr], w0[3], acc[rr][3]);
          acc[rr][4] = fmaf(v[rr], w1[0], acc[rr][4]);
          acc[rr][5] = fmaf(v[rr], w1[1], acc[rr][5]);
          acc[rr][6] = fmaf(v[rr], w1[2], acc[rr][6]);
          acc[rr][7] = fmaf(v[rr], w1[3], acc[rr][7]);
        }
      }

#pragma unroll
  for (int rr = 0; rr < 4; rr++) {
    short8v hv;
#pragma unroll
    for (int j = 0; j < 8; j++) hv[j] = (short)f2bf(lrelu(acc[rr][j]));
    *(short8v*)(h1 + (((size_t)b*512 + ty0+py4+rr)*512 + tx0+px)*8) = hv;
  }
}

// ---------------------------------------------------------------------------
// Implicit-GEMM MFMA conv. in: NHWC bf16 (unpadded, bounds-checked).
// wmfma: [(b)][chunk][oc][32] bf16. out: NHWC bf16 pre-BN (+bias).
// A-frag: 16 consecutive ox in one row; lane reads 8 contiguous ic.
// ---------------------------------------------------------------------------
template <int IC, int OC, int KSZ, int S, int P, int CPR, int NCH,
          int IH, int IW, int OWL, int WM, int WN, int WVM, int WVN, bool PERS>
__global__ __launch_bounds__(WVM*WVN*64) void conv_mfma(
    const u16* __restrict__ in, const u16* __restrict__ wmfma,
    const float* __restrict__ bias, u16* __restrict__ out) {
  constexpr int OW = 1 << OWL;
  const int tid = threadIdx.x, lane = tid & 63;
  const int w = tid >> 6, wm = w % WVM, wn = w / WVM;
  const int l15 = lane & 15, sub = lane >> 4;
  const int b = blockIdx.z;
  const int px0 = blockIdx.x * (16*WM*WVM) + wm * (16*WM);
  const int oc0 = blockIdx.y * (16*WN*WVN) + wn * (16*WN);

  int oyf[WM], oxb[WM];
#pragma unroll
  for (int f = 0; f < WM; f++) {
    int p = px0 + f*16;
    oyf[f] = p >> OWL;
    oxb[f] = p & (OW-1);
  }
  const u16* wbase = wmfma + (PERS ? (size_t)b*NCH*OC*32 : (size_t)0);
  const short8v az = {0,0,0,0,0,0,0,0};

  float4v acc[WM][WN];
#pragma unroll
  for (int f = 0; f < WM; f++)
#pragma unroll
    for (int n = 0; n < WN; n++) acc[f][n] = (float4v){0.f,0.f,0.f,0.f};

#pragma unroll
  for (int ky = 0; ky < KSZ; ky++) {
#pragma unroll
    for (int r = 0; r < CPR; r++) {
      const int c = ky*CPR + r;
      const int kk0 = r*32 + sub*8;
      const int kx = kk0 / IC;
      const int icoff = kk0 % IC;
      short8v B[WN];
#pragma unroll
      for (int n = 0; n < WN; n++)
        B[n] = *(const short8v*)(wbase + ((size_t)c*OC + oc0 + n*16 + l15)*32 + sub*8);
      short8v A[WM];
#pragma unroll
      for (int f = 0; f < WM; f++) {
        int iy = S*oyf[f] + ky - P;
        int ix = S*(oxb[f] + l15) + kx - P;
        bool ok = (iy >= 0) & (iy < IH) & (ix >= 0) & (ix < IW);
        const short8v* pa = (const short8v*)(in + (((size_t)b*IH + iy)*IW + ix)*IC + icoff);
        A[f] = ok ? *pa : az;
      }
#pragma unroll
      for (int f = 0; f < WM; f++)
#pragma unroll
        for (int n = 0; n < WN; n++)
          acc[f][n] = __builtin_amdgcn_mfma_f32_16x16x32_bf16(A[f], B[n], acc[f][n], 0, 0, 0);
    }
  }

#pragma unroll
  for (int f = 0; f < WM; f++) {
    const int oxs = oxb[f] + sub*4;
    const size_t rowb = ((size_t)b*OW + oyf[f])*OW;   // OH == OW
#pragma unroll
    for (int n = 0; n < WN; n++) {
      int oc = oc0 + n*16 + l15;
      float bv = bias[oc];
#pragma unroll
      for (int rr = 0; rr < 4; rr++) {
        float v = acc[f][n][rr] + bv;
        out[(rowb + oxs + rr)*OC + oc] = f2bf(v);
      }
    }
  }
}

// ---------------------------------------------------------------------------
// BN stats over NHWC: stage1 partial (per-block, per-channel sum/sumsq),
// stage2 -> (scale, shift), finalize in-place (+lrelu).
// ---------------------------------------------------------------------------
template <int C>
__global__ __launch_bounds__(256) void bn_stage1(const u16* __restrict__ y,
                                                 float* __restrict__ part, int iters) {
  const int t = threadIdx.x;
  size_t base = (size_t)blockIdx.x * iters * 1024 + t*4;
  float s0=0,s1=0,s2=0,s3=0,q0=0,q1=0,q2=0,q3=0;
  for (int i = 0; i < iters; i++) {
    ushort4 u = *(const ushort4*)(y + base + (size_t)i*1024);
    float v0=bf2f(u.x), v1=bf2f(u.y), v2=bf2f(u.z), v3=bf2f(u.w);
    s0+=v0; s1+=v1; s2+=v2; s3+=v3;
    q0+=v0*v0; q1+=v1*v1; q2+=v2*v2; q3+=v3*v3;
  }
  __shared__ float red[256*8];
  red[t*8+0]=s0; red[t*8+1]=s1; red[t*8+2]=s2; red[t*8+3]=s3;
  red[t*8+4]=q0; red[t*8+5]=q1; red[t*8+6]=q2; red[t*8+7]=q3;
  __syncthreads();
  if (t < 2*C) {
    int c = t >> 1, isq = t & 1;
    float a = 0.f;
    for (int j = 0; j < 1024/C; j++) {
      int tt = (c >> 2) + j*(C >> 2);
      a += red[tt*8 + (c & 3) + isq*4];
    }
    part[(size_t)blockIdx.x*2*C + t] = a;
  }
}

__global__ void bn_stage2(const float* __restrict__ part, const float* __restrict__ g,
                          const float* __restrict__ bb, float* __restrict__ stats,
                          int NB, int C, float invN) {
  int c = blockIdx.x;
  float s = 0.f, q = 0.f;
  for (int i = threadIdx.x; i < NB; i += 64) {
    s += part[(size_t)i*2*C + 2*c];
    q += part[(size_t)i*2*C + 2*c + 1];
  }
  for (int o = 32; o > 0; o >>= 1) { s += __shfl_down(s, o); q += __shfl_down(q, o); }
  if (threadIdx.x == 0) {
    float m = s * invN;
    float var = q * invN - m*m;
    float sc = g[c] * rsqrtf(var + BN_EPS);
    stats[2*c] = sc;
    stats[2*c+1] = bb[c] - m*sc;
  }
}

__global__ __launch_bounds__(256) void bn_fin(u16* __restrict__ y, const float* __restrict__ stats,
                                              int total8, int Cm1) {
  int i = blockIdx.x*256 + threadIdx.x;
  if (i >= total8) return;
  size_t e = (size_t)i*8;
  int c0 = (int)(e & (size_t)Cm1);
  short8v u = *(short8v*)(y + e);
  short8v o;
#pragma unroll
  for (int j = 0; j < 8; j++) {
    float v = bf2f((u16)u[j]) * stats[2*(c0+j)] + stats[2*(c0+j)+1];
    o[j] = (short)f2bf(lrelu(v));
  }
  *(short8v*)(y + e) = o;
}

// final: lrelu(bn(yT6)) NHWC bf16 -> NCHW fp32 d_out
__global__ __launch_bounds__(256) void out_k(const u16* __restrict__ y6,
                                             const float* __restrict__ stats,
                                             float* __restrict__ out) {
  int i = blockIdx.x*256 + threadIdx.x;
  if (i >= 131072) return;
  size_t e = (size_t)i*4;
  int c0 = (int)(e & 127);
  int px = (int)((e >> 7) & 255);
  int b  = (int)(e >> 15);
  ushort4 u = *(const ushort4*)(y6 + e);
  float vv[4] = {bf2f(u.x), bf2f(u.y), bf2f(u.z), bf2f(u.w)};
#pragma unroll
  for (int j = 0; j < 4; j++) {
    int c = c0 + j;
    float v = vv[j] * stats[2*c] + stats[2*c+1];
    out[((size_t)b*128 + c)*256 + px] = lrelu(v);
  }
}

// ---------------------------------------------------------------------------
extern "C" void kernel_launch(void* const* d_in, const int* in_sizes, int n_in,
                              void* d_out, int out_size, void* d_ws, size_t ws_size,
                              hipStream_t stream) {
  const float* x    = (const float*)d_in[0];
  const float* cw   = (const float*)d_in[1];
  const float* w11  = (const float*)d_in[2];
  const float* b11  = (const float*)d_in[3];
  const float* w12  = (const float*)d_in[4];
  const float* b12  = (const float*)d_in[5];
  const float* bn1g = (const float*)d_in[6];
  const float* bn1b = (const float*)d_in[7];
  const float* c2w[4] = {(const float*)d_in[8], (const float*)d_in[12],
                         (const float*)d_in[16], (const float*)d_in[20]};
  const float* c2b[4] = {(const float*)d_in[9], (const float*)d_in[13],
                         (const float*)d_in[17], (const float*)d_in[21]};
  const float* bng[4] = {(const float*)d_in[10], (const float*)d_in[14],
                         (const float*)d_in[18], (const float*)d_in[22]};
  const float* bnb[4] = {(const float*)d_in[11], (const float*)d_in[15],
                         (const float*)d_in[19], (const float*)d_in[23]};

  char* ws = (char*)d_ws;
  // Region A [0, 67.1MB): h1 during L1/L2; later y3/y4/y5/y6 + shared weights + stats.
  u16* h1   = (u16*)(ws);
  u16* y3   = (u16*)(ws);                         // 16.78 MB
  u16* y4   = (u16*)(ws + 16777216);              // 8.39 MB
  u16* y5   = (u16*)(ws + 25165824);              // 4.19 MB
  u16* y6   = (u16*)(ws + 29360128);              // 1.05 MB
  u16* wS1  = (u16*)(ws + 41943040);              // 30720 B
  u16* wS2  = (u16*)(ws + 41984000);              // 102400 B
  u16* wS3  = (u16*)(ws + 42086400);              // 147456 B
  u16* wS4  = (u16*)(ws + 42233856);              // 294912 B
  float* part   = (float*)(ws + 50331648);        // <=131072 B
  float* stats2 = (float*)(ws + 50462720);
  float* stats3 = stats2 + 32;
  float* stats4 = stats3 + 64;
  float* stats5 = stats4 + 128;
  float* stats6 = stats5 + 256;
  // Region B [67.1MB, 100.7MB): xpad during L1 prep, then yT2.
  u16* xpad = (u16*)(ws + 67108864);              // 25.71 MB
  u16* yT2  = (u16*)(ws + 67108864);              // 33.55 MB
  // Tail [100.66MB, ~100.83MB): L2 meta weights + biases (needed while h1+yT2 live).
  u16* wl2m = (u16*)(ws + 100663296);             // 163840 B
  float* bl1 = (float*)(ws + 100827136);
  float* bl2 = bl1 + 16;

  hipMemsetAsync(xpad, 0, (size_t)16*517*518*3*2, stream);
  convert_x<<<16384, 256, 0, stream>>>(x, xpad);
  prep_bias<<<1, 64, 0, stream>>>(b11, b12, bl1, bl2);
  prep_l2m<<<320, 256, 0, stream>>>(w12, cw, wl2m);

  // L1: 3->8 k5 s1, per-sample -> h1 (post-lrelu NHWC)
  conv_l1<<<dim3(256, 1, 16), 256, 0, stream>>>(xpad, w11, cw, bl1, h1);

  // L2: 8->16 k5 s2, per-sample meta weights -> yT2 (pre-BN)
  conv_mfma<8,16,5,2,2, 2,10, 512,512,8, 4,1,4,1, true>
      <<<dim3(256,1,16), 256, 0, stream>>>(h1, wl2m, bl2, yT2);

  // shared-weight packs (region A — launched after L2 in stream order)
  prep_w<16,32,5,3,15><<<60, 256, 0, stream>>>(c2w[0], wS1);
  prep_w<32,64,5,5,25><<<200, 256, 0, stream>>>(c2w[1], wS2);
  prep_w<64,128,3,6,18><<<288, 256, 0, stream>>>(c2w[2], wS3);
  prep_w<128,128,3,12,36><<<576, 256, 0, stream>>>(c2w[3], wS4);

  // BN1 on yT2 (C=16, N=16*65536)
  bn_stage1<16><<<512, 256, 0, stream>>>(yT2, part, 32);
  bn_stage2<<<16, 64, 0, stream>>>(part, bn1g, bn1b, stats2, 512, 16, 1.f/1048576.f);
  bn_fin<<<8192, 256, 0, stream>>>(yT2, stats2, 2097152, 15);

  // S1: 16->32 k5 s2 -> y3
  conv_mfma<16,32,5,2,2, 3,15, 256,256,7, 2,2,4,1, false>
      <<<dim3(128,1,16), 256, 0, stream>>>(yT2, wS1, c2b[0], y3);
  bn_stage1<32><<<512, 256, 0, stream>>>(y3, part, 16);
  bn_stage2<<<32, 64, 0, stream>>>(part, bng[0], bnb[0], stats3, 512, 32, 1.f/262144.f);
  bn_fin<<<4096, 256, 0, stream>>>(y3, stats3, 1048576, 31);

  // S2: 32->64 k5 s2 -> y4
  conv_mfma<32,64,5,2,2, 5,25, 128,128,6, 2,2,2,2, false>
      <<<dim3(64,1,16), 256, 0, stream>>>(y3, wS2, c2b[1], y4);
  bn_stage1<64><<<256, 256, 0, stream>>>(y4, part, 16);
  bn_stage2<<<64, 64, 0, stream>>>(part, bng[1], bnb[1], stats4, 256, 64, 1.f/65536.f);
  bn_fin<<<2048, 256, 0, stream>>>(y4, stats4, 524288, 63);

  // S3: 64->128 k3 s2 -> y5
  conv_mfma<64,128,3,2,1, 6,18, 64,64,5, 2,2,2,2, false>
      <<<dim3(16,2,16), 256, 0, stream>>>(y4, wS3, c2b[2], y5);
  bn_stage1<128><<<128, 256, 0, stream>>>(y5, part, 16);
  bn_stage2<<<128, 64, 0, stream>>>(part, bng[2], bnb[2], stats5, 128, 128, 1.f/16384.f);
  bn_fin<<<1024, 256, 0, stream>>>(y5, stats5, 262144, 127);

  // S4: 128->128 k3 s2 -> y6 (pre-BN)
  conv_mfma<128,128,3,2,1, 12,36, 32,32,4, 2,2,1,2, false>
      <<<dim3(8,2,16), 128, 0, stream>>>(y5, wS4, c2b[3], y6);
  bn_stage1<128><<<64, 256, 0, stream>>>(y6, part, 8);
  bn_stage2<<<128, 64, 0, stream>>>(part, bng[3], bnb[3], stats6, 64, 128, 1.f/4096.f);

  out_k<<<512, 256, 0, stream>>>(y6, stats6, (float*)d_out);
}